// Round 5
// baseline (41.096 us; speedup 1.0000x reference)
//
#include <hip/hip_runtime.h>

#define NQ 5
#define NL 6
#define NG 4
#define DIM 32
#define PATCH 16
#define SPITCH 20   // floats per batch in LDS staging (16 + pad; 80 B keeps f4 align)

// CZ-chain sign: flip amplitude i iff # adjacent set-bit pairs is odd.
__device__ __forceinline__ int flip_par(int i) {
    int p = i & (i >> 1) & 0xF;
    p ^= p >> 2; p ^= p >> 1;
    return p & 1;
}

// Stage 1: M_g[r,i] = weight-circuit operator, rows 0..15 (q0=0 slice).
// 128 threads: thread = (g<<5)|col simulates basis vector e_col. Verified R1-R4.
__global__ void build_M(const float* __restrict__ qp, float* __restrict__ M) {
    const float RV = 0.07957747154594767f; // 0.5/(2*pi): v_sin/v_cos take revolutions
    const int tid = threadIdx.x;
    if (tid >= NG * DIM) return;
    const int g = tid >> 5, col = tid & 31;
    float st[DIM];
    #pragma unroll
    for (int i = 0; i < DIM; ++i) st[i] = (i == col) ? 1.0f : 0.0f;
    #pragma unroll 1
    for (int l = 0; l < NL; ++l) {
        #pragma unroll          // w unrolled: st[] indices stay compile-time
        for (int w = 0; w < NQ; ++w) {
            float h = qp[g*(NL*NQ) + l*NQ + w] * RV;
            float c = __builtin_amdgcn_cosf(h);
            float s = __builtin_amdgcn_sinf(h);
            const int bit = 4 - w, str = 1 << bit;
            #pragma unroll
            for (int p = 0; p < 16; ++p) {
                int lo = ((p >> bit) << (bit + 1)) | (p & (str - 1));
                int hi = lo + str;
                float a0 = st[lo], a1 = st[hi];
                st[lo] = c*a0 - s*a1;
                st[hi] = s*a0 + c*a1;
            }
        }
        if (l != NL - 1) {      // outermost sign layer dies in |.|^2
            #pragma unroll
            for (int i = 0; i < DIM; ++i)
                if (flip_par(i)) st[i] = -st[i];
        }
    }
    #pragma unroll
    for (int r = 0; r < PATCH; ++r)
        M[(g*PATCH + r)*DIM + col] = st[r];
}

// One 32-length dot: row chunk rq (float4 index) against lane-private base[32].
// Wave-uniform address -> single L1 request + broadcast. All indices static.
__device__ __forceinline__ float dot_row(const float4* __restrict__ M4, int rq,
                                         const float* base) {
    float4 m[8];
    #pragma unroll
    for (int q = 0; q < 8; ++q) m[q] = M4[rq + q];
    float a0 = 0.f, a1 = 0.f, a2 = 0.f, a3 = 0.f;
    #pragma unroll
    for (int q = 0; q < 8; ++q) {
        a0 = fmaf(m[q].x, base[4*q+0], a0);
        a1 = fmaf(m[q].y, base[4*q+1], a1);
        a2 = fmaf(m[q].z, base[4*q+2], a2);
        a3 = fmaf(m[q].w, base[4*q+3], a3);
    }
    return (a0 + a1) + (a2 + a3);
}

// Stage 2: lane = batch. base[32] private in VGPRs; M rows via broadcast VMEM
// (L1-resident). p = amp^2, out = p / max_r p (sum normalization cancels).
// LDS only for the per-wave transpose so global stores are coalesced float4.
__global__ __launch_bounds__(256, 4) void qgen4(
        const float* __restrict__ x, const float* __restrict__ M,
        float* __restrict__ out) {
    __shared__ __align__(16) float stg[4][64 * SPITCH + 64];  // 21.5 KB

    const int t = threadIdx.x;
    const int wid = t >> 6, lane = t & 63;
    const int b0 = (blockIdx.x * 4 + wid) * 64;

    const float RV = 0.07957747154594767f;
    float cn[NQ], sn[NQ];
    const float* xp = x + (size_t)(b0 + lane) * NQ;
    #pragma unroll
    for (int w = 0; w < NQ; ++w) {
        float h = xp[w] * RV;
        cn[w] = __builtin_amdgcn_cosf(h);
        sn[w] = __builtin_amdgcn_sinf(h);
    }
    // product state of the noise RYs (62 mults), private per lane
    float base[DIM];
    base[0] = cn[0]; base[1] = sn[0];
    #pragma unroll
    for (int w = 1; w < NQ; ++w) {
        #pragma unroll
        for (int j = (1 << w) - 1; j >= 0; --j) {
            float v = base[j];
            base[2*j + 1] = v * sn[w];
            base[2*j]     = v * cn[w];
        }
    }

    const float4* M4 = (const float4*)M;   // row r chunk q at M4[r*8 + q]
    float* sw  = stg[wid];
    float* inw = sw + 64 * SPITCH;
    float* ow  = out + (size_t)b0 * 64;

    #pragma unroll 1
    for (int g = 0; g < NG; ++g) {
        float mx = 0.0f;                   // p >= 0: safe identity
        #pragma unroll 1
        for (int c = 0; c < 4; ++c) {      // chunk = 4 rows -> one b128 write
            const int rb = (g * PATCH + c * 4) * 8;
            float ampA = dot_row(M4, rb,      base);
            float ampB = dot_row(M4, rb + 8,  base);
            float ampC = dot_row(M4, rb + 16, base);
            float ampD = dot_row(M4, rb + 24, base);
            float p0 = ampA * ampA, p1 = ampB * ampB;
            float p2 = ampC * ampC, p3 = ampD * ampD;
            mx = fmaxf(fmaxf(mx, fmaxf(p0, p1)), fmaxf(p2, p3));
            *(float4*)&sw[lane * SPITCH + c * 4] = make_float4(p0, p1, p2, p3);
        }
        inw[lane] = __builtin_amdgcn_rcpf(mx);
        // Same-wave DS ordering (each wave touches only its own slice; the
        // compiler inserts the lgkmcnt). No block barrier anywhere.
        #pragma unroll
        for (int j = 0; j < 4; ++j) {
            int bl = (lane >> 2) + 16 * j;   // local batch
            int f  = lane & 3;               // float4 slot
            float4 v = *(const float4*)&sw[bl * SPITCH + f * 4];
            float iv = inw[bl];
            *(float4*)&ow[bl*64 + g*16 + f*4] =
                make_float4(v.x*iv, v.y*iv, v.z*iv, v.w*iv);
        }
    }
}

extern "C" void kernel_launch(void* const* d_in, const int* in_sizes, int n_in,
                              void* d_out, int out_size, void* d_ws, size_t ws_size,
                              hipStream_t stream) {
    const float* x  = (const float*)d_in[0];
    const float* qp = (const float*)d_in[1];
    float* out = (float*)d_out;
    float* M = (float*)d_ws;               // 8 KB scratch
    const int B = in_sizes[0] / NQ;
    build_M<<<1, 128, 0, stream>>>(qp, M);
    qgen4<<<B / 256, 256, 0, stream>>>(x, M, out);
}

// Round 6
// 35.995 us; speedup vs baseline: 1.1417x; 1.1417x over previous
//
#include <hip/hip_runtime.h>

#define NQ 5
#define NL 6
#define NG 4
#define DIM 32
#define PATCH 16

typedef __attribute__((ext_vector_type(16))) float f16v;

// CZ-chain sign: flip amplitude i iff # adjacent set-bit pairs is odd.
__device__ __forceinline__ int flip_par(int i) {
    int p = i & (i >> 1) & 0xF;
    p ^= p >> 2; p ^= p >> 1;
    return p & 1;
}

// Stage 1: M_g[r,i] = weight-circuit operator, rows 0..15 (q0=0 slice).
// 128 threads: thread = (g<<5)|col simulates basis vector e_col. Verified R1-R5.
__global__ void build_M(const float* __restrict__ qp, float* __restrict__ M) {
    const float RV = 0.07957747154594767f; // 0.5/(2*pi): v_sin/v_cos take revolutions
    const int tid = threadIdx.x;
    if (tid >= NG * DIM) return;
    const int g = tid >> 5, col = tid & 31;
    float st[DIM];
    #pragma unroll
    for (int i = 0; i < DIM; ++i) st[i] = (i == col) ? 1.0f : 0.0f;
    #pragma unroll 1
    for (int l = 0; l < NL; ++l) {
        #pragma unroll          // w unrolled: st[] indices stay compile-time
        for (int w = 0; w < NQ; ++w) {
            float h = qp[g*(NL*NQ) + l*NQ + w] * RV;
            float c = __builtin_amdgcn_cosf(h);
            float s = __builtin_amdgcn_sinf(h);
            const int bit = 4 - w, str = 1 << bit;
            #pragma unroll
            for (int p = 0; p < 16; ++p) {
                int lo = ((p >> bit) << (bit + 1)) | (p & (str - 1));
                int hi = lo + str;
                float a0 = st[lo], a1 = st[hi];
                st[lo] = c*a0 - s*a1;
                st[hi] = s*a0 + c*a1;
            }
        }
        if (l != NL - 1) {      // outermost sign layer dies in |.|^2
            #pragma unroll
            for (int i = 0; i < DIM; ++i)
                if (flip_par(i)) st[i] = -st[i];
        }
    }
    #pragma unroll
    for (int r = 0; r < PATCH; ++r)
        M[(g*PATCH + r)*DIM + col] = st[r];
}

// Load TWO M rows (64 floats) into SGPRs via s_load_dwordx16 and wait inside
// the asm (outputs are only valid after lgkmcnt(0); keeping the wait in the
// same asm block makes the data dependency airtight). Early-clobber so the
// outputs can't alias the address pair.
__device__ __forceinline__ void load2rows_s(const float* mp, f16v& a0, f16v& a1,
                                            f16v& b0, f16v& b1) {
    asm("s_load_dwordx16 %0, %4, 0x0\n\t"
        "s_load_dwordx16 %1, %4, 0x40\n\t"
        "s_load_dwordx16 %2, %4, 0x80\n\t"
        "s_load_dwordx16 %3, %4, 0xc0\n\t"
        "s_waitcnt lgkmcnt(0)"
        : "=&s"(a0), "=&s"(a1), "=&s"(b0), "=&s"(b1)
        : "s"(mp));
}

// dot of one row (two x16 SGPR halves) against lane-private base[32].
// fmaf(s, v, v) -> v_fmac_f32 with the SGPR in src0 (1 SGPR operand: legal).
__device__ __forceinline__ float dot_s(const f16v& lo, const f16v& hi,
                                       const float* base) {
    float u0 = 0.f, u1 = 0.f, u2 = 0.f, u3 = 0.f;
    #pragma unroll
    for (int q = 0; q < 4; ++q) {
        u0 = fmaf(lo[4*q+0], base[4*q+0], u0);
        u1 = fmaf(lo[4*q+1], base[4*q+1], u1);
        u2 = fmaf(lo[4*q+2], base[4*q+2], u2);
        u3 = fmaf(lo[4*q+3], base[4*q+3], u3);
    }
    #pragma unroll
    for (int q = 0; q < 4; ++q) {
        u0 = fmaf(hi[4*q+0], base[16+4*q+0], u0);
        u1 = fmaf(hi[4*q+1], base[16+4*q+1], u1);
        u2 = fmaf(hi[4*q+2], base[16+4*q+2], u2);
        u3 = fmaf(hi[4*q+3], base[16+4*q+3], u3);
    }
    return (u0 + u1) + (u2 + u3);
}

// Stage 2: lane = batch. base[32] in VGPRs; M rows stream through SGPRs
// (scalar cache, one 16B return per wave -- no 64-lane replication).
// p = amp^2; out = p / max_r p (sum normalization cancels).
__global__ __launch_bounds__(256, 4) void qgen5(
        const float* __restrict__ x, const float* __restrict__ M,
        float* __restrict__ out) {
    // per-wave staging: [16 slots][65] floats (stride 65 -> <=2-way bank alias)
    __shared__ float stg[4][16 * 65];
    __shared__ float inv_s[4][64];

    const int t = threadIdx.x;
    const int wid = t >> 6, lane = t & 63;
    const int b0 = (blockIdx.x * 4 + wid) * 64;

    const float RV = 0.07957747154594767f;
    float cn[NQ], sn[NQ];
    const float* xp = x + (size_t)(b0 + lane) * NQ;
    #pragma unroll
    for (int w = 0; w < NQ; ++w) {
        float h = xp[w] * RV;
        cn[w] = __builtin_amdgcn_cosf(h);
        sn[w] = __builtin_amdgcn_sinf(h);
    }
    // product state of the noise RYs (62 mults), private per lane
    float base[DIM];
    base[0] = cn[0]; base[1] = sn[0];
    #pragma unroll
    for (int w = 1; w < NQ; ++w) {
        #pragma unroll
        for (int j = (1 << w) - 1; j >= 0; --j) {
            float v = base[j];
            base[2*j + 1] = v * sn[w];
            base[2*j]     = v * cn[w];
        }
    }

    float* sw  = stg[wid];
    float* inw = inv_s[wid];
    float* ow  = out + (size_t)b0 * 64;

    #pragma unroll 1
    for (int g = 0; g < NG; ++g) {
        float mx = 0.0f;                   // p >= 0: safe identity
        #pragma unroll 1
        for (int c = 0; c < 4; ++c) {      // chunk = 4 rows
            const float* mp = M + (g * PATCH + c * 4) * DIM;
            f16v a0, a1, b0v, b1v;
            load2rows_s(mp, a0, a1, b0v, b1v);        // rows 4c, 4c+1
            float ampA = dot_s(a0, a1, base);
            float ampB = dot_s(b0v, b1v, base);
            load2rows_s(mp + 2*DIM, a0, a1, b0v, b1v); // rows 4c+2, 4c+3
            float ampC = dot_s(a0, a1, base);
            float ampD = dot_s(b0v, b1v, base);
            float p0 = ampA*ampA, p1 = ampB*ampB;
            float p2 = ampC*ampC, p3 = ampD*ampD;
            mx = fmaxf(fmaxf(mx, fmaxf(p0, p1)), fmaxf(p2, p3));
            sw[(c*4 + 0)*65 + lane] = p0;  // b32 writes, lane-stride 1: no conflicts
            sw[(c*4 + 1)*65 + lane] = p1;
            sw[(c*4 + 2)*65 + lane] = p2;
            sw[(c*4 + 3)*65 + lane] = p3;
        }
        inw[lane] = __builtin_amdgcn_rcpf(mx);
        // Same-wave DS RAW: in-order per wave, compiler inserts lgkmcnt.
        // Each wave touches only its own slice -> no barrier anywhere.
        #pragma unroll
        for (int j = 0; j < 4; ++j) {
            int bl = (lane >> 2) + 16 * j;   // local batch
            int f  = lane & 3;               // float4 slot
            float v0 = sw[(4*f + 0)*65 + bl];
            float v1 = sw[(4*f + 1)*65 + bl];
            float v2 = sw[(4*f + 2)*65 + bl];
            float v3 = sw[(4*f + 3)*65 + bl];
            float iv = inw[bl];
            *(float4*)&ow[bl*64 + g*16 + f*4] =
                make_float4(v0*iv, v1*iv, v2*iv, v3*iv);
        }
    }
}

extern "C" void kernel_launch(void* const* d_in, const int* in_sizes, int n_in,
                              void* d_out, int out_size, void* d_ws, size_t ws_size,
                              hipStream_t stream) {
    const float* x  = (const float*)d_in[0];
    const float* qp = (const float*)d_in[1];
    float* out = (float*)d_out;
    float* M = (float*)d_ws;               // 8 KB scratch
    const int B = in_sizes[0] / NQ;
    build_M<<<1, 128, 0, stream>>>(qp, M);
    qgen5<<<B / 256, 256, 0, stream>>>(x, M, out);
}

// Round 7
// 28.616 us; speedup vs baseline: 1.4361x; 1.2579x over previous
//
#include <hip/hip_runtime.h>

#define NQ 5
#define NL 6
#define NG 4
#define DIM 32
#define PATCH 16

typedef _Float16 half8 __attribute__((ext_vector_type(8)));
typedef float f32x4 __attribute__((ext_vector_type(4)));

// CZ-chain sign: flip amplitude i iff # adjacent set-bit pairs is odd.
__device__ __forceinline__ int flip_par(int i) {
    int p = i & (i >> 1) & 0xF;
    p ^= p >> 2; p ^= p >> 1;
    return p & 1;
}

// Stage 1: M_g[r,i] = weight-circuit operator, rows 0..15 (q0=0 slice).
// 128 threads: thread = (g<<5)|col simulates basis vector e_col. Verified R1-R6.
__global__ void build_M(const float* __restrict__ qp, float* __restrict__ M) {
    const float RV = 0.07957747154594767f; // 0.5/(2*pi): v_sin/v_cos take revolutions
    const int tid = threadIdx.x;
    if (tid >= NG * DIM) return;
    const int g = tid >> 5, col = tid & 31;
    float st[DIM];
    #pragma unroll
    for (int i = 0; i < DIM; ++i) st[i] = (i == col) ? 1.0f : 0.0f;
    #pragma unroll 1
    for (int l = 0; l < NL; ++l) {
        #pragma unroll          // w unrolled: st[] indices stay compile-time
        for (int w = 0; w < NQ; ++w) {
            float h = qp[g*(NL*NQ) + l*NQ + w] * RV;
            float c = __builtin_amdgcn_cosf(h);
            float s = __builtin_amdgcn_sinf(h);
            const int bit = 4 - w, str = 1 << bit;
            #pragma unroll
            for (int p = 0; p < 16; ++p) {
                int lo = ((p >> bit) << (bit + 1)) | (p & (str - 1));
                int hi = lo + str;
                float a0 = st[lo], a1 = st[hi];
                st[lo] = c*a0 - s*a1;
                st[hi] = s*a0 + c*a1;
            }
        }
        if (l != NL - 1) {      // outermost sign layer dies in |.|^2
            #pragma unroll
            for (int i = 0; i < DIM; ++i)
                if (flip_par(i)) st[i] = -st[i];
        }
    }
    #pragma unroll
    for (int r = 0; r < PATCH; ++r)
        M[(g*PATCH + r)*DIM + col] = st[r];
}

// Stage 2: D[slot,batch] = M · base via mfma_f32_16x16x32_f16, f16 hi/lo split
// (3 MFMA per tile; residual error ~2e-6). A-frag = M rows (register-resident);
// B-frag = per-batch product state, relayed through LDS into fragment order.
// K-layout of A/B frags uses the SAME (lane>>4, elem)->k map on both operands,
// so any internal HW k-permutation cancels. D layout (verified m89):
// col = lane&15 (batch), row = (lane>>4)*4 + reg (slot) -> the 16-slot max is
// 3 in-lane fmax + shfl_xor(16) + shfl_xor(32); each lane stores one float4.
__global__ __launch_bounds__(256, 4) void qgen6(
        const float* __restrict__ x, const float* __restrict__ M,
        float* __restrict__ out) {
    __shared__ float4 relay[4][8][64];     // 32 KB: per-wave base relay

    const int t = threadIdx.x;
    const int wid = t >> 6, lane = t & 63;
    const int l15 = lane & 15, kg = lane >> 4;
    const int b0 = (blockIdx.x * 4 + wid) * 64;

    // ---- A-fragments: M rows, f16 split, loaded once (L2-hot, 2 KB/g/wave)
    half8 MhA[NG], MlA[NG];
    #pragma unroll
    for (int g = 0; g < NG; ++g) {
        const float* mp = M + (g * PATCH + l15) * DIM + kg * 8;
        float m8[8];
        *(float4*)&m8[0] = *(const float4*)&mp[0];
        *(float4*)&m8[4] = *(const float4*)&mp[4];
        half8 h, lo;
        #pragma unroll
        for (int e = 0; e < 8; ++e) {
            _Float16 hh = (_Float16)m8[e];
            h[e]  = hh;
            lo[e] = (_Float16)(m8[e] - (float)hh);
        }
        MhA[g] = h; MlA[g] = lo;
    }

    // ---- per-lane trig + product state (lane = batch b0+lane). Verified R1-R6.
    const float RV = 0.07957747154594767f;
    float cn[NQ], sn[NQ];
    const float* xp = x + (size_t)(b0 + lane) * NQ;
    #pragma unroll
    for (int w = 0; w < NQ; ++w) {
        float h = xp[w] * RV;
        cn[w] = __builtin_amdgcn_cosf(h);
        sn[w] = __builtin_amdgcn_sinf(h);
    }
    float base[DIM];
    base[0] = cn[0]; base[1] = sn[0];
    #pragma unroll
    for (int w = 1; w < NQ; ++w) {
        #pragma unroll
        for (int j = (1 << w) - 1; j >= 0; --j) {
            float v = base[j];
            base[2*j + 1] = v * sn[w];
            base[2*j]     = v * cn[w];
        }
    }

    // ---- relay base -> B-fragment order (same-wave RAW, in-order DS; the
    // compiler inserts the lgkmcnt. No barrier: wave-private slice.)
    #pragma unroll
    for (int q = 0; q < 8; ++q)
        relay[wid][q][lane] = *(float4*)&base[q * 4];

    half8 BhF[4], BlF[4];
    #pragma unroll
    for (int tb = 0; tb < 4; ++tb) {
        float4 r0 = relay[wid][kg*2 + 0][tb*16 + l15];
        float4 r1 = relay[wid][kg*2 + 1][tb*16 + l15];
        float b8[8] = {r0.x, r0.y, r0.z, r0.w, r1.x, r1.y, r1.z, r1.w};
        half8 h, lo;
        #pragma unroll
        for (int e = 0; e < 8; ++e) {
            _Float16 hh = (_Float16)b8[e];
            h[e]  = hh;
            lo[e] = (_Float16)(b8[e] - (float)hh);
        }
        BhF[tb] = h; BlF[tb] = lo;
    }

    // ---- 16 tiles x 3 MFMA + epilogue. All indices compile-time (rule #20).
    float* ob = out + (size_t)b0 * 64;
    #pragma unroll
    for (int g = 0; g < NG; ++g) {
        #pragma unroll
        for (int tb = 0; tb < 4; ++tb) {
            f32x4 acc = {0.f, 0.f, 0.f, 0.f};
            acc = __builtin_amdgcn_mfma_f32_16x16x32_f16(MhA[g], BhF[tb], acc, 0, 0, 0);
            acc = __builtin_amdgcn_mfma_f32_16x16x32_f16(MlA[g], BhF[tb], acc, 0, 0, 0);
            acc = __builtin_amdgcn_mfma_f32_16x16x32_f16(MhA[g], BlF[tb], acc, 0, 0, 0);
            float p0 = acc[0]*acc[0], p1 = acc[1]*acc[1];
            float p2 = acc[2]*acc[2], p3 = acc[3]*acc[3];
            float mx = fmaxf(fmaxf(p0, p1), fmaxf(p2, p3));
            mx = fmaxf(mx, __shfl_xor(mx, 16, 64));
            mx = fmaxf(mx, __shfl_xor(mx, 32, 64));
            float inv = __builtin_amdgcn_rcpf(mx);
            // lane stores slots kg*4..kg*4+3 of batch (tb*16+l15): one float4;
            // the wave covers 16 batches x 64 B; 4 g-stores merge to full lines.
            *(float4*)&ob[(tb*16 + l15)*64 + g*16 + kg*4] =
                make_float4(p0*inv, p1*inv, p2*inv, p3*inv);
        }
    }
}

extern "C" void kernel_launch(void* const* d_in, const int* in_sizes, int n_in,
                              void* d_out, int out_size, void* d_ws, size_t ws_size,
                              hipStream_t stream) {
    const float* x  = (const float*)d_in[0];
    const float* qp = (const float*)d_in[1];
    float* out = (float*)d_out;
    float* M = (float*)d_ws;               // 8 KB scratch
    const int B = in_sizes[0] / NQ;
    build_M<<<1, 128, 0, stream>>>(qp, M);
    qgen6<<<B / 256, 256, 0, stream>>>(x, M, out);
}